// Round 12
// baseline (44.141 us; speedup 1.0000x reference)
//
#include <hip/hip_runtime.h>
#include <hip/hip_bf16.h>
#include <math.h>

#define NB   16
#define CIN  64
#define LEN  8192
#define LP2  8195     // rows: 0 = left pad(0), 1..8192 = x, 8193/8194 = right pad(0)
#define COUT 64
#define MSZ  192

typedef float    f32x4 __attribute__((ext_vector_type(4)));
typedef _Float16 f16x8 __attribute__((ext_vector_type(8)));
typedef _Float16 f16x2 __attribute__((ext_vector_type(2)));

static __device__ inline unsigned int pkrtz(float lo, float hi) {
    return __builtin_bit_cast(unsigned int, __builtin_amdgcn_cvt_pkrtz(lo, hi)); // low16=lo, high16=hi
}

// ---------------- Kernel P3: fused offset-conv + f16 transpose + wfrag ----------------
// blocks 0..511: (n = bid>>5, t = bid&31) tile = 256 l x 64 ch, 512 threads.
//   lane owns 4 consecutive l (float4 loads, taps from register window + shfl);
//   wave wid owns channels 8*wid..+7 (wave-uniform weight addresses -> s_load).
// blocks 512..535: pack w into MFMA B-fragment order (f16).
__global__ __launch_bounds__(512) void prep3_kernel(
    const float* __restrict__ x, const float* __restrict__ w_off,
    const float* __restrict__ b_off, const float* __restrict__ w,
    float* __restrict__ gbuf, unsigned int* __restrict__ xt32,
    unsigned short* __restrict__ wtf)
{
    int bid = blockIdx.x;
    int tid = threadIdx.x;

    if (bid >= NB * 32) {
        // ---- wfrag: b = ot*6 + ks ----
        int b = bid - NB * 32;           // 0..23
        int ot = b / 6, ks = b - ot * 6;
        int lq = tid >> 3, s = tid & 7;
        int o = ot * 16 + (lq & 15);
        int m = ks * 32 + (lq >> 4) * 8 + s;
        _Float16 h = (_Float16)w[o * MSZ + m];
        wtf[b * 512 + tid] = __builtin_bit_cast(unsigned short, h);
        return;
    }

    __shared__ unsigned int bt[256 * 33];   // 33.8 KB, transposed f16x2
    __shared__ float ps[8][3][256];         // 24 KB, conv partials

    int lane = tid & 63;
    int wid  = __builtin_amdgcn_readfirstlane(tid >> 6);   // 0..7
    int n  = bid >> 5;
    int t  = bid & 31;
    int l0 = t << 8;
    int lbase = l0 + (lane << 2);
    const float* xn = x + (size_t)n * (CIN * LEN);

    float ak[3][4] = {};
    unsigned int pk[4][4];

    #pragma unroll
    for (int pr = 0; pr < 4; ++pr) {
        int c0 = (wid << 3) + (pr << 1);
        const float* xc0 = xn + (size_t)c0 * LEN;
        const float* xc1 = xc0 + LEN;
        float4 v0 = *(const float4*)&xc0[lbase];
        float4 v1 = *(const float4*)&xc1[lbase];

        float eL0 = 0.f, eL1 = 0.f, eR0 = 0.f, eR1 = 0.f;
        if (lane == 0 && l0 > 0)          { eL0 = xc0[l0 - 1];   eL1 = xc1[l0 - 1]; }
        if (lane == 63 && l0 + 256 < LEN) { eR0 = xc0[l0 + 256]; eR1 = xc1[l0 + 256]; }
        float pw0 = __shfl_up(v0.w, 1);   if (lane == 0)  pw0 = eL0;
        float pw1 = __shfl_up(v1.w, 1);   if (lane == 0)  pw1 = eL1;
        float nx0 = __shfl_down(v0.x, 1); if (lane == 63) nx0 = eR0;
        float nx1 = __shfl_down(v1.x, 1); if (lane == 63) nx1 = eR1;

        float t0[6] = { pw0, v0.x, v0.y, v0.z, v0.w, nx0 };
        float t1[6] = { pw1, v1.x, v1.y, v1.z, v1.w, nx1 };

        const float* wa = w_off + (size_t)c0 * 3;   // offset out-ch 0 (k=0)
        const float* wb = wa + 384;                 // out-ch 2 (k=1)
        const float* wc = wa + 768;                 // out-ch 4 (k=2)

        #pragma unroll
        for (int li = 0; li < 4; ++li) {
            float xm0 = t0[li], x00 = t0[li + 1], xp0 = t0[li + 2];
            float xm1 = t1[li], x01 = t1[li + 1], xp1 = t1[li + 2];
            float a0 = ak[0][li], a1 = ak[1][li], a2 = ak[2][li];
            a0 = fmaf(wa[0], xm0, a0); a0 = fmaf(wa[1], x00, a0); a0 = fmaf(wa[2], xp0, a0);
            a0 = fmaf(wa[3], xm1, a0); a0 = fmaf(wa[4], x01, a0); a0 = fmaf(wa[5], xp1, a0);
            a1 = fmaf(wb[0], xm0, a1); a1 = fmaf(wb[1], x00, a1); a1 = fmaf(wb[2], xp0, a1);
            a1 = fmaf(wb[3], xm1, a1); a1 = fmaf(wb[4], x01, a1); a1 = fmaf(wb[5], xp1, a1);
            a2 = fmaf(wc[0], xm0, a2); a2 = fmaf(wc[1], x00, a2); a2 = fmaf(wc[2], xp0, a2);
            a2 = fmaf(wc[3], xm1, a2); a2 = fmaf(wc[4], x01, a2); a2 = fmaf(wc[5], xp1, a2);
            ak[0][li] = a0; ak[1][li] = a1; ak[2][li] = a2;
            pk[li][pr] = pkrtz(t0[li + 1], t1[li + 1]);   // low = even ch, high = odd ch
        }
    }

    #pragma unroll
    for (int k = 0; k < 3; ++k)
        *(float4*)&ps[wid][k][lane << 2] = make_float4(ak[k][0], ak[k][1], ak[k][2], ak[k][3]);

    // bt writes: row = 4*lane+li, col-block = wid*4 (u32 units), XOR swizzle by lane>>3
    {
        int sw   = ((lane >> 3) & 7) << 2;
        int colb = wid << 2;
        #pragma unroll
        for (int li = 0; li < 4; ++li) {
            int row = (lane << 2) + li;
            *(uint4*)&bt[row * 33 + (colb ^ sw)] =
                make_uint4(pk[li][0], pk[li][1], pk[li][2], pk[li][3]);
        }
    }
    __syncthreads();

    // gbuf: thread = l (first 256 threads)
    if (tid < 256) {
        int l = tid;
        #pragma unroll
        for (int k = 0; k < 3; ++k) {
            float s = b_off[2 * k];
            #pragma unroll
            for (int w8 = 0; w8 < 8; ++w8) s += ps[w8][k][l];
            float g = fminf(fmaxf((float)(l0 + l + 1) + s, 0.f), 8193.f);
            gbuf[((size_t)n * LEN + l0 + l) * 3 + k] = g;
        }
    }

    // xt writeout: row = tid>>1, 16 u32 half-row per thread (4 uint4)
    {
        int row = tid >> 1;
        int gq  = (tid & 1) << 2;                 // uint4-group base: 0 or 4
        int swr = ((row >> 5) & 7) << 2;
        size_t gb = ((size_t)n * LP2 + 1 + l0 + row) * 32 + (gq << 2);
        #pragma unroll
        for (int g = 0; g < 4; ++g) {
            uint4 u = *(const uint4*)&bt[row * 33 + (((gq + g) << 2) ^ swr)];
            *(uint4*)&xt32[gb + (g << 2)] = u;
        }
    }
    if (t == 0  && tid < 32) xt32[((size_t)n * LP2) * 32 + tid] = 0u;
    if (t == 31 && tid < 64) xt32[((size_t)n * LP2 + 8193 + (tid >> 5)) * 32 + (tid & 31)] = 0u;
}

// ---------------- Kernel D8: dconv6 structure, f16 packed-lerp + f16 MFMA ----------------
__global__ __launch_bounds__(256) void dconv8_kernel(
    const unsigned short* __restrict__ xt16, const unsigned short* __restrict__ wtf,
    const float* __restrict__ bias, const float* __restrict__ gbuf,
    float* __restrict__ out)
{
    __shared__ unsigned short Bl[MSZ * 64];    // 24 KB
    __shared__ __align__(16) int2 meta[MSZ];
    int tid = threadIdx.x;

    // bijective XCD swizzle: XCD x = wg&7 serves only n in {2x, 2x+1}
    int wg  = blockIdx.x;
    int xcd = wg & 7;
    int tt  = wg >> 3;
    int n   = (xcd << 1) | (tt >> 7);
    int p   = tt & 127;

    if (tid < MSZ) {
        int k = tid >> 6, r = tid & 63;
        int l = (r << 7) | p;
        float g  = gbuf[((size_t)n * LEN + l) * 3 + k];
        float fl = floorf(g);
        meta[tid] = make_int2((int)fl, __float_as_int(g - fl));
    }
    __syncthreads();

    const unsigned short* xb = xt16 + (size_t)n * LP2 * 64;

    // stage B: task = (m, 8-channel chunk); single barrier, all loads overlapped
    #pragma unroll
    for (int j = 0; j < 6; ++j) {
        int task = tid + (j << 8);       // 0..1535
        int m  = task >> 3;
        int ch = task & 7;
        int2 mv = meta[m];
        float a = __int_as_float(mv.y);
        _Float16 ah = (_Float16)a;
        f16x2 a2; a2[0] = ah; a2[1] = ah;
        const unsigned short* rl = xb + ((size_t)(unsigned)mv.x << 6) + (ch << 3);
        uint4 vl4 = *(const uint4*)rl;
        uint4 vr4 = *(const uint4*)(rl + 64);
        const f16x2* vlh = (const f16x2*)&vl4;
        const f16x2* vrh = (const f16x2*)&vr4;
        uint4 ov;
        unsigned int* ovp = (unsigned int*)&ov;
        #pragma unroll
        for (int q = 0; q < 4; ++q) {
            f16x2 r = vlh[q] + a2 * (vrh[q] - vlh[q]);   // v_pk_{sub,fma}_f16
            ovp[q] = __builtin_bit_cast(unsigned int, r);
        }
        int dst = (m << 6) + ((ch << 3) ^ (((m >> 3) & 3) << 4));
        *(uint4*)&Bl[dst] = ov;
    }
    __syncthreads();

    int lane = tid & 63;
    int ct   = tid >> 6;
    int g4   = lane >> 4;
    int c    = (ct << 4) | (lane & 15);

    f32x4 acc[4] = {};

    #pragma unroll
    for (int ks = 0; ks < 6; ++ks) {
        int mb = ks * 32 + (g4 << 3);
        int cx = c ^ ((((unsigned)(mb >> 3)) & 3) << 4);
        f16x8 afrag;
        #pragma unroll
        for (int s = 0; s < 8; ++s)
            afrag[s] = __builtin_bit_cast(_Float16, Bl[((mb + s) << 6) + cx]);

        #pragma unroll
        for (int ot = 0; ot < 4; ++ot) {
            f16x8 bfrag = *(const f16x8*)(wtf + ((size_t)(((ot * 6 + ks) << 6) + lane) << 3));
            acc[ot] = __builtin_amdgcn_mfma_f32_16x16x32_f16(afrag, bfrag, acc[ot], 0, 0, 0);
        }
    }

    // D layout: col(o) = lane&15, row(c-block) = (lane>>4)*4 + reg
    int q0 = (p << 6) + ct * 16 + g4 * 4;
    #pragma unroll
    for (int ot = 0; ot < 4; ++ot) {
        int o = ot * 16 + (lane & 15);
        float bb = bias[o];
        float4 r4;
        r4.x = acc[ot][0] + bb;
        r4.y = acc[ot][1] + bb;
        r4.z = acc[ot][2] + bb;
        r4.w = acc[ot][3] + bb;
        *(float4*)&out[((size_t)n * COUT + o) * LEN + q0] = r4;
    }
}

extern "C" void kernel_launch(void* const* d_in, const int* in_sizes, int n_in,
                              void* d_out, int out_size, void* d_ws, size_t ws_size,
                              hipStream_t stream) {
    const float* x     = (const float*)d_in[0];
    const float* w_off = (const float*)d_in[1];
    const float* b_off = (const float*)d_in[2];
    const float* w     = (const float*)d_in[3];
    const float* b     = (const float*)d_in[4];
    float* out = (float*)d_out;

    const size_t GBUF_B = (size_t)NB * LEN * 3 * sizeof(float);     // 6,291,456
    const size_t WTF_B  = (size_t)MSZ * COUT * sizeof(short);       // 24,576
    float*          gbuf = (float*)d_ws;
    unsigned short* wtf  = (unsigned short*)((char*)d_ws + GBUF_B);
    unsigned int*   xt32 = (unsigned int*)((char*)d_ws + GBUF_B + WTF_B);
    unsigned short* xt16 = (unsigned short*)xt32;

    prep3_kernel<<<NB * 32 + 24, 512, 0, stream>>>(x, w_off, b_off, w, gbuf, xt32, wtf);
    dconv8_kernel<<<NB * 128, 256, 0, stream>>>(xt16, wtf, b, gbuf, out);
}

// Round 13
// 33.584 us; speedup vs baseline: 1.3143x; 1.3143x over previous
//
#include <hip/hip_runtime.h>
#include <hip/hip_bf16.h>
#include <math.h>

#define NB   16
#define CIN  64
#define LEN  8192
#define LP2  8195     // rows: 0 = left pad(0), 1..8192 = x, 8193/8194 = right pad(0)
#define COUT 64
#define MSZ  192

typedef float    f32x4 __attribute__((ext_vector_type(4)));
typedef _Float16 f16x8 __attribute__((ext_vector_type(8)));
typedef _Float16 f16x2 __attribute__((ext_vector_type(2)));

static __device__ inline unsigned int pkrtz(float lo, float hi) {
    return __builtin_bit_cast(unsigned int, __builtin_amdgcn_cvt_pkrtz(lo, hi)); // low16=lo, high16=hi
}

// ---------------- Kernel P4: R8 prep structure + f16 pack + XCD-aligned mapping ----------------
// blocks 0..2047: XCD-swizzled (n,t); tile = 64 l x 64 ch, 256 threads.
//   XCD x writes xt for n in {2x,2x+1} -> same XCD that gathers it in dconv8 (L2-resident).
// blocks 2048..2071: pack w into MFMA B-fragment order (f16).
__global__ __launch_bounds__(256) void prep4_kernel(
    const float* __restrict__ x, const float* __restrict__ w_off,
    const float* __restrict__ b_off, const float* __restrict__ w,
    float* __restrict__ gbuf, unsigned int* __restrict__ xt32,
    unsigned short* __restrict__ wtf)
{
    int bid = blockIdx.x;
    int tid = threadIdx.x;

    if (bid >= NB * 128) {
        // ---- wfrag: b = ot*6 + ks ----
        int b = bid - NB * 128;          // 0..23
        int ot = b / 6, ks = b - ot * 6;
        #pragma unroll
        for (int h = 0; h < 2; ++h) {
            int t2 = tid + h * 256;
            int lq = t2 >> 3, s = t2 & 7;
            int o = ot * 16 + (lq & 15);
            int m = ks * 32 + (lq >> 4) * 8 + s;
            _Float16 hv = (_Float16)w[o * MSZ + m];
            wtf[b * 512 + t2] = __builtin_bit_cast(unsigned short, hv);
        }
        return;
    }

    __shared__ float ps[4][3][64];
    __shared__ unsigned int bt[64 * 33];

    int lane = tid & 63;
    int wid  = __builtin_amdgcn_readfirstlane(tid >> 6);
    // XCD-aligned mapping: same bijective swizzle as dconv8
    int xcd = bid & 7;
    int tt  = bid >> 3;               // 0..255
    int n   = (xcd << 1) | (tt >> 7);
    int t   = tt & 127;
    int l0 = t << 6;
    int l  = l0 + lane;
    const float* xn = x + (size_t)n * (CIN * LEN);
    bool okm = (l >= 1);
    bool okp = (l < LEN - 1);

    float a0 = 0.f, a1 = 0.f, a2 = 0.f;
    unsigned int pk[8];

    #pragma unroll
    for (int ci = 0; ci < 16; ci += 2) {
        int c0 = (wid << 4) | ci;
        const float* xc0 = xn + (size_t)c0 * LEN;
        const float* xc1 = xc0 + LEN;
        float xm0 = okm ? xc0[l - 1] : 0.f;
        float x00 = xc0[l];
        float xp0 = okp ? xc0[l + 1] : 0.f;
        float xm1 = okm ? xc1[l - 1] : 0.f;
        float x01 = xc1[l];
        float xp1 = okp ? xc1[l + 1] : 0.f;
        const float* wa = w_off + (size_t)c0 * 3;
        const float* wb = wa + 384;
        const float* wc = wa + 768;
        a0 = fmaf(wa[0], xm0, a0); a0 = fmaf(wa[1], x00, a0); a0 = fmaf(wa[2], xp0, a0);
        a0 = fmaf(wa[3], xm1, a0); a0 = fmaf(wa[4], x01, a0); a0 = fmaf(wa[5], xp1, a0);
        a1 = fmaf(wb[0], xm0, a1); a1 = fmaf(wb[1], x00, a1); a1 = fmaf(wb[2], xp0, a1);
        a1 = fmaf(wb[3], xm1, a1); a1 = fmaf(wb[4], x01, a1); a1 = fmaf(wb[5], xp1, a1);
        a2 = fmaf(wc[0], xm0, a2); a2 = fmaf(wc[1], x00, a2); a2 = fmaf(wc[2], xp0, a2);
        a2 = fmaf(wc[3], xm1, a2); a2 = fmaf(wc[4], x01, a2); a2 = fmaf(wc[5], xp1, a2);
        pk[ci >> 1] = pkrtz(x00, x01);   // low = even ch, high = odd ch
    }

    ps[wid][0][lane] = a0;
    ps[wid][1][lane] = a1;
    ps[wid][2][lane] = a2;
    #pragma unroll
    for (int j = 0; j < 8; ++j)
        bt[lane * 33 + (wid << 3) + j] = pk[j];
    __syncthreads();

    if (tid < 192) {
        int k = tid >> 6, ll = tid & 63;
        float s = b_off[2 * k];
        #pragma unroll
        for (int w4 = 0; w4 < 4; ++w4) s += ps[w4][k][ll];
        float g = fminf(fmaxf((float)(l0 + ll + 1) + s, 0.f), 8193.f);
        gbuf[((size_t)n * LEN + l0 + ll) * 3 + k] = g;
    }

    {
        int row = tid >> 2, grp = tid & 3;
        const unsigned int* src = &bt[row * 33 + (grp << 3)];
        uint4 u0, u1;
        u0.x = src[0]; u0.y = src[1]; u0.z = src[2]; u0.w = src[3];
        u1.x = src[4]; u1.y = src[5]; u1.z = src[6]; u1.w = src[7];
        size_t base = ((size_t)n * LP2 + 1 + l0 + row) * 32 + (grp << 3);
        *(uint4*)&xt32[base]     = u0;
        *(uint4*)&xt32[base + 4] = u1;
    }
    if (t == 0   && tid < 32) xt32[((size_t)n * LP2) * 32 + tid] = 0u;
    if (t == 127 && tid < 64) xt32[((size_t)n * LP2 + 8193 + (tid >> 5)) * 32 + (tid & 31)] = 0u;
}

// ---------------- Kernel D8 (unchanged from R12): LDS-staged B + f16 packed-lerp + f16 MFMA ----------------
__global__ __launch_bounds__(256) void dconv8_kernel(
    const unsigned short* __restrict__ xt16, const unsigned short* __restrict__ wtf,
    const float* __restrict__ bias, const float* __restrict__ gbuf,
    float* __restrict__ out)
{
    __shared__ unsigned short Bl[MSZ * 64];    // 24 KB
    __shared__ __align__(16) int2 meta[MSZ];
    int tid = threadIdx.x;

    // bijective XCD swizzle: XCD x = wg&7 serves only n in {2x, 2x+1}
    int wg  = blockIdx.x;
    int xcd = wg & 7;
    int tt  = wg >> 3;
    int n   = (xcd << 1) | (tt >> 7);
    int p   = tt & 127;

    if (tid < MSZ) {
        int k = tid >> 6, r = tid & 63;
        int l = (r << 7) | p;
        float g  = gbuf[((size_t)n * LEN + l) * 3 + k];
        float fl = floorf(g);
        meta[tid] = make_int2((int)fl, __float_as_int(g - fl));
    }
    __syncthreads();

    const unsigned short* xb = xt16 + (size_t)n * LP2 * 64;

    // stage B: task = (m, 8-channel chunk); single barrier, all loads overlapped
    #pragma unroll
    for (int j = 0; j < 6; ++j) {
        int task = tid + (j << 8);       // 0..1535
        int m  = task >> 3;
        int ch = task & 7;
        int2 mv = meta[m];
        float a = __int_as_float(mv.y);
        _Float16 ah = (_Float16)a;
        f16x2 a2; a2[0] = ah; a2[1] = ah;
        const unsigned short* rl = xb + ((size_t)(unsigned)mv.x << 6) + (ch << 3);
        uint4 vl4 = *(const uint4*)rl;
        uint4 vr4 = *(const uint4*)(rl + 64);
        const f16x2* vlh = (const f16x2*)&vl4;
        const f16x2* vrh = (const f16x2*)&vr4;
        uint4 ov;
        unsigned int* ovp = (unsigned int*)&ov;
        #pragma unroll
        for (int q = 0; q < 4; ++q) {
            f16x2 r = vlh[q] + a2 * (vrh[q] - vlh[q]);   // v_pk_{sub,fma}_f16
            ovp[q] = __builtin_bit_cast(unsigned int, r);
        }
        int dst = (m << 6) + ((ch << 3) ^ (((m >> 3) & 3) << 4));
        *(uint4*)&Bl[dst] = ov;
    }
    __syncthreads();

    int lane = tid & 63;
    int ct   = tid >> 6;
    int g4   = lane >> 4;
    int c    = (ct << 4) | (lane & 15);

    f32x4 acc[4] = {};

    #pragma unroll
    for (int ks = 0; ks < 6; ++ks) {
        int mb = ks * 32 + (g4 << 3);
        int cx = c ^ ((((unsigned)(mb >> 3)) & 3) << 4);
        f16x8 afrag;
        #pragma unroll
        for (int s = 0; s < 8; ++s)
            afrag[s] = __builtin_bit_cast(_Float16, Bl[((mb + s) << 6) + cx]);

        #pragma unroll
        for (int ot = 0; ot < 4; ++ot) {
            f16x8 bfrag = *(const f16x8*)(wtf + ((size_t)(((ot * 6 + ks) << 6) + lane) << 3));
            acc[ot] = __builtin_amdgcn_mfma_f32_16x16x32_f16(afrag, bfrag, acc[ot], 0, 0, 0);
        }
    }

    // D layout: col(o) = lane&15, row(c-block) = (lane>>4)*4 + reg
    int q0 = (p << 6) + ct * 16 + g4 * 4;
    #pragma unroll
    for (int ot = 0; ot < 4; ++ot) {
        int o = ot * 16 + (lane & 15);
        float bb = bias[o];
        float4 r4;
        r4.x = acc[ot][0] + bb;
        r4.y = acc[ot][1] + bb;
        r4.z = acc[ot][2] + bb;
        r4.w = acc[ot][3] + bb;
        *(float4*)&out[((size_t)n * COUT + o) * LEN + q0] = r4;
    }
}

extern "C" void kernel_launch(void* const* d_in, const int* in_sizes, int n_in,
                              void* d_out, int out_size, void* d_ws, size_t ws_size,
                              hipStream_t stream) {
    const float* x     = (const float*)d_in[0];
    const float* w_off = (const float*)d_in[1];
    const float* b_off = (const float*)d_in[2];
    const float* w     = (const float*)d_in[3];
    const float* b     = (const float*)d_in[4];
    float* out = (float*)d_out;

    const size_t GBUF_B = (size_t)NB * LEN * 3 * sizeof(float);     // 6,291,456
    const size_t WTF_B  = (size_t)MSZ * COUT * sizeof(short);       // 24,576
    float*          gbuf = (float*)d_ws;
    unsigned short* wtf  = (unsigned short*)((char*)d_ws + GBUF_B);
    unsigned int*   xt32 = (unsigned int*)((char*)d_ws + GBUF_B + WTF_B);
    unsigned short* xt16 = (unsigned short*)xt32;

    prep4_kernel<<<NB * 128 + 24, 256, 0, stream>>>(x, w_off, b_off, w, gbuf, xt32, wtf);
    dconv8_kernel<<<NB * 128, 256, 0, stream>>>(xt16, wtf, b, gbuf, out);
}